// Round 4
// baseline (30.802 us; speedup 1.0000x reference)
//
#include <hip/hip_runtime.h>
#include <hip/hip_fp16.h>
#include <math.h>

#define NUM_HEADS 16
#define DIM_HID 64
#define NUM_GAUSS 251
#define E_FEAT 5
#define W_SCA_COLS 320   // DIM_HID + 256
#define NROWS 126        // gaussian g-pair rows: row r covers g=2r, 2r+1
#define RSTRIDE 20       // half2 per row (16 data + 4 pad) = 80 B, 16B-aligned
#define RAD 0.16f        // window radius: dropped terms < exp(-8)*|w| ~ 2e-5

// ---------------------------------------------------------------------------
// Self-contained per-edge kernel. One thread per edge, 128-thread blocks.
//
// Algebraic collapse (validated r2/r3: absmax 3.9e-3 vs 1.57e-2 threshold):
//   weff[h] = w_vec1[h,:] @ w_edge                     (input-independent)
//   vnorm block of out_sca = ||unit|| * A[o],  A = |weff| @ w_sca[:, :64]^T
//   out_vec[o,i] = B[o]*unit[i] -> output_vec = (sigmoid*B)^2 * ||unit||^2
// A,B recomputed per block (no d_ws cross-kernel state — round-1 lesson).
//
// Round-4: gauss loop was LDS-pipe bound (72 ds_read_b128/wave).
//   - f16 packed g-PAIR table: one 4x b128 row read covers TWO g values,
//     accumulated with __hfma2 (v_pk_fma_f16). 72 -> ~20 b128/wave.
//   - radius 0.34 -> 0.16 (error ~5e-5, budget 1.2e-2).
//   - 128-thr blocks: 1563 blocks -> 6.1/CU, tail imbalance 33% -> 17%.
// ---------------------------------------------------------------------------
__global__ __launch_bounds__(128) void edge_kernel(
    const int* __restrict__ idxA,     // [E]
    const int* __restrict__ idxB,     // [E]
    const float* __restrict__ feat,   // [E,5]
    const float* __restrict__ pos,    // [N,3]
    const float* __restrict__ w_edge, // [64]
    const float* __restrict__ w_vec1, // [64,64]
    const float* __restrict__ w_vec2, // [16,64]
    const float* __restrict__ w_sca,  // [16,320]
    const float* __restrict__ w_gate, // [16,16]
    const float* __restrict__ b_gate, // [16]
    float* __restrict__ out,
    int E)
{
    __shared__ __align__(16) __half2 wgt[NROWS * RSTRIDE]; // [r][head] = (wg[2r], wg[2r+1])
    __shared__ __align__(16) float weff[64];
    __shared__ float As[16], Bs[16];

    const int tid = threadIdx.x;

    // --- stage f16 pair table: 16 heads x 126 rows = 2016 half2 ---
    for (int j = tid; j < NUM_HEADS * NROWS; j += 128) {
        int o = j / NROWS;           // magic-mul
        int r = j - o * NROWS;
        // float2 load: 8B-aligned (64+2r even). r=125: src[1] is etype col -> zero it.
        float2 v = *(const float2*)(w_sca + o * W_SCA_COLS + DIM_HID + 2 * r);
        float hi = (r < 125) ? v.y : 0.f;
        wgt[r * RSTRIDE + o] = __floats2half2_rn(v.x, hi);
    }

    // --- per-block fold of input-independent algebra ---
    if (tid < 64) {
        const float4* wrow = (const float4*)(w_vec1 + tid * 64);
        float s = 0.f;
        #pragma unroll
        for (int c4 = 0; c4 < 16; ++c4) {
            float4 v = wrow[c4];
            s += v.x * w_edge[c4 * 4 + 0] + v.y * w_edge[c4 * 4 + 1]
               + v.z * w_edge[c4 * 4 + 2] + v.w * w_edge[c4 * 4 + 3];
        }
        weff[tid] = s;
    }
    __syncthreads();
    if (tid < 16) {
        const float4* srow = (const float4*)(w_sca + tid * W_SCA_COLS);
        const float4* vrow = (const float4*)(w_vec2 + tid * 64);
        float a = 0.f, b = 0.f;
        #pragma unroll
        for (int k4 = 0; k4 < 16; ++k4) {
            float4 sv = srow[k4];
            float4 vv = vrow[k4];
            float4 wv = *(const float4*)&weff[k4 * 4];
            a += fabsf(wv.x) * sv.x + fabsf(wv.y) * sv.y + fabsf(wv.z) * sv.z + fabsf(wv.w) * sv.w;
            b += wv.x * vv.x + wv.y * vv.y + wv.z * vv.z + wv.w * vv.w;
        }
        As[tid] = a;
        Bs[tid] = b;
    }
    __syncthreads();

    const int e = blockIdx.x * 128 + tid;
    if (e >= E) return;

    const int a = idxA[e];
    const int b = idxB[e];
    const float ax = pos[a * 3 + 0], ay = pos[a * 3 + 1], az = pos[a * 3 + 2];
    const float bx = pos[b * 3 + 0], by = pos[b * 3 + 1], bz = pos[b * 3 + 2];
    const float vx = ax - bx, vy = ay - by, vz = az - bz;
    const float d2 = vx * vx + vy * vy + vz * vz;
    const float d  = sqrtf(d2);
    const float un = d / (d + 1e-7f);      // ||unit||

    // --- gaussian window over g-pair rows, f16 packed accumulate ---
    __half2 hacc[16];
    #pragma unroll
    for (int o = 0; o < 16; ++o) hacc[o] = __floats2half2_rn(0.f, 0.f);

    int glo = (int)ceilf((d - RAD) * 25.f);
    if (glo < 0) glo = 0;
    int ghi = (int)floorf((d + RAD) * 25.f);
    if (ghi > NUM_GAUSS - 1) ghi = NUM_GAUSS - 1;
    int rlo = glo >> 1;
    int rhi = ghi >> 1;                    // rlo > rhi when window empty (d > 10.16)

    const float C2 = -312.5f * 1.44269504088896340736f;   // coeff * log2(e)
    for (int r = rlo; r <= rhi; ++r) {
        const float ta = d - (float)r * 0.08f;
        const float tb = ta - 0.04f;
        const float w0 = exp2f(C2 * ta * ta);
        const float w1 = exp2f(C2 * tb * tb);
        const __half2 w2 = __floats2half2_rn(w0, w1);
        const float4* row = (const float4*)&wgt[r * RSTRIDE];
        union { float4 f; __half2 h[4]; } u0, u1, u2, u3;
        u0.f = row[0]; u1.f = row[1]; u2.f = row[2]; u3.f = row[3];
        hacc[0]  = __hfma2(w2, u0.h[0], hacc[0]);
        hacc[1]  = __hfma2(w2, u0.h[1], hacc[1]);
        hacc[2]  = __hfma2(w2, u0.h[2], hacc[2]);
        hacc[3]  = __hfma2(w2, u0.h[3], hacc[3]);
        hacc[4]  = __hfma2(w2, u1.h[0], hacc[4]);
        hacc[5]  = __hfma2(w2, u1.h[1], hacc[5]);
        hacc[6]  = __hfma2(w2, u1.h[2], hacc[6]);
        hacc[7]  = __hfma2(w2, u1.h[3], hacc[7]);
        hacc[8]  = __hfma2(w2, u2.h[0], hacc[8]);
        hacc[9]  = __hfma2(w2, u2.h[1], hacc[9]);
        hacc[10] = __hfma2(w2, u2.h[2], hacc[10]);
        hacc[11] = __hfma2(w2, u2.h[3], hacc[11]);
        hacc[12] = __hfma2(w2, u3.h[0], hacc[12]);
        hacc[13] = __hfma2(w2, u3.h[1], hacc[13]);
        hacc[14] = __hfma2(w2, u3.h[2], hacc[14]);
        hacc[15] = __hfma2(w2, u3.h[3], hacc[15]);
    }

    // --- assemble out_sca: vnorm block + gauss + edge-type block ---
    float acc[16];
    #pragma unroll
    for (int o = 0; o < 16; ++o)
        acc[o] = fmaf(un, As[o], __low2float(hacc[o]) + __high2float(hacc[o]));

    #pragma unroll
    for (int t = 0; t < E_FEAT; ++t) {
        const float f = feat[e * E_FEAT + t];
        #pragma unroll
        for (int o = 0; o < 16; ++o)
            acc[o] += f * w_sca[o * W_SCA_COLS + DIM_HID + NUM_GAUSS + t];  // uniform -> s_load
    }

    // --- gates: w_gate/b_gate via uniform s_load; sigmoid via exp2 + fast rcp ---
    const float u2 = un * un;
    const float NL2E = -1.44269504088896340736f;
    float outv[16];
    #pragma unroll
    for (int o = 0; o < 16; ++o) {
        float x = b_gate[o];
        #pragma unroll
        for (int p = 0; p < 16; ++p) x += acc[p] * w_gate[o * 16 + p];
        const float gate = __builtin_amdgcn_rcpf(1.0f + exp2f(NL2E * x));
        const float gv = gate * Bs[o];
        outv[o] = gv * gv * u2;
    }

    // --- coalesced stores (2 x 64B per thread) ---
    float* o1 = out + (size_t)e * 16;
    float* o2 = out + (size_t)E * 16 + (size_t)e * 16;
    #pragma unroll
    for (int o = 0; o < 16; o += 4) {
        *(float4*)(o1 + o) = make_float4(acc[o], acc[o + 1], acc[o + 2], acc[o + 3]);
        *(float4*)(o2 + o) = make_float4(outv[o], outv[o + 1], outv[o + 2], outv[o + 3]);
    }
}

extern "C" void kernel_launch(void* const* d_in, const int* in_sizes, int n_in,
                              void* d_out, int out_size, void* d_ws, size_t ws_size,
                              hipStream_t stream) {
    const int*   idx    = (const int*)d_in[0];    // [2,E]
    const float* feat   = (const float*)d_in[1];  // [E,5]
    const float* pos    = (const float*)d_in[2];  // [N,3]
    const float* w_edge = (const float*)d_in[3];  // [64,1]
    const float* w_vec1 = (const float*)d_in[4];  // [64,64]
    const float* w_vec2 = (const float*)d_in[5];  // [16,64]
    const float* w_sca  = (const float*)d_in[6];  // [16,320]
    const float* w_gate = (const float*)d_in[7];  // [16,16]
    const float* b_gate = (const float*)d_in[8];  // [16]
    float* out = (float*)d_out;

    const int E = in_sizes[0] / 2;
    const int nblk = (E + 127) / 128;
    edge_kernel<<<nblk, 128, 0, stream>>>(idx, idx + E, feat, pos,
                                          w_edge, w_vec1, w_vec2,
                                          w_sca, w_gate, b_gate, out, E);
}

// Round 5
// 23.980 us; speedup vs baseline: 1.2845x; 1.2845x over previous
//
#include <hip/hip_runtime.h>
#include <math.h>

#define NUM_HEADS 16
#define DIM_HID 64
#define NUM_GAUSS 251
#define E_FEAT 5
#define W_SCA_COLS 320   // DIM_HID + 256
#define GP 20            // padded stride (floats): 80B, 16B-aligned, bank-base pattern spreads 8 ways
#define RAD 0.16f        // window radius: dropped terms < exp(-8)*|w| ~ 2e-5 each

// ---------------------------------------------------------------------------
// Self-contained per-edge kernel. One thread per edge, 256-thread blocks.
// (Round-3 structure = measured 25.5 us; round-4's f16/128-thr bundle
//  regressed to 30.8 and is reverted.)
//
// Algebraic collapse (validated: absmax 3.9e-3 vs 1.57e-2 threshold):
//   weff[h] = w_vec1[h,:] @ w_edge                    (input-independent)
//   vnorm block of out_sca = ||unit|| * A[o],  A = |weff| @ w_sca[:, :64]^T
//   out_vec[o,i] = B[o]*unit[i] -> output_vec = (sigmoid*B)^2 * ||unit||^2
// A,B recomputed per block (no d_ws cross-kernel state — round-1 lesson).
//
// Round-5 deltas (isolated, low-risk):
//   - RAD 0.34 -> 0.16: gauss iters 18 -> 9 (LDS b128 72 -> 36, exp2 18 -> 9)
//   - __launch_bounds__(256,4): cap VGPR <= 128 -> >= 4 waves/SIMD (m69 cliff)
//   - idx/feat loads hoisted above staging (latency hides under prologue)
//   - rcpf sigmoid; out_sca stored before gate pass (earlier reg retirement)
// ---------------------------------------------------------------------------
__global__ __launch_bounds__(256, 4) void edge_kernel(
    const int* __restrict__ idxA,     // [E]
    const int* __restrict__ idxB,     // [E]
    const float* __restrict__ feat,   // [E,5]
    const float* __restrict__ pos,    // [N,3]
    const float* __restrict__ w_edge, // [64]
    const float* __restrict__ w_vec1, // [64,64]
    const float* __restrict__ w_vec2, // [16,64]
    const float* __restrict__ w_sca,  // [16,320]
    const float* __restrict__ w_gate, // [16,16]
    const float* __restrict__ b_gate, // [16]
    float* __restrict__ out,
    int E)
{
    __shared__ __align__(16) float wg[NUM_GAUSS * GP]; // gauss slice, transposed: row g holds 16 heads
    __shared__ __align__(16) float weff[64];
    __shared__ float As[16], Bs[16];

    const int tid = threadIdx.x;
    const int e = blockIdx.x * 256 + tid;
    const bool active = (e < E);
    const int ec = active ? e : (E - 1);   // clamp so inactive lanes load safely

    // --- early-issue per-edge loads: latency hides under the staging below ---
    const int a = idxA[ec];
    const int b = idxB[ec];
    float f[E_FEAT];
    #pragma unroll
    for (int t = 0; t < E_FEAT; ++t) f[t] = feat[ec * E_FEAT + t];

    // --- stage gauss weight slice (contiguous global reads, scattered LDS writes) ---
    for (int j = tid; j < 16 * NUM_GAUSS; j += 256) {
        int o = j / NUM_GAUSS;          // magic-mul
        int g = j - o * NUM_GAUSS;
        wg[g * GP + o] = w_sca[o * W_SCA_COLS + DIM_HID + g];
    }

    // --- per-block fold of input-independent algebra (float4 loads) ---
    if (tid < 64) {
        const float4* wrow = (const float4*)(w_vec1 + tid * 64);
        float s = 0.f;
        #pragma unroll
        for (int c4 = 0; c4 < 16; ++c4) {
            float4 v = wrow[c4];
            s += v.x * w_edge[c4 * 4 + 0] + v.y * w_edge[c4 * 4 + 1]
               + v.z * w_edge[c4 * 4 + 2] + v.w * w_edge[c4 * 4 + 3];
        }
        weff[tid] = s;
    }
    __syncthreads();
    if (tid < 16) {
        const float4* srow = (const float4*)(w_sca + tid * W_SCA_COLS);
        const float4* vrow = (const float4*)(w_vec2 + tid * 64);
        float a2 = 0.f, b2 = 0.f;
        #pragma unroll
        for (int k4 = 0; k4 < 16; ++k4) {
            float4 sv = srow[k4];
            float4 vv = vrow[k4];
            float4 wv = *(const float4*)&weff[k4 * 4];
            a2 += fabsf(wv.x) * sv.x + fabsf(wv.y) * sv.y + fabsf(wv.z) * sv.z + fabsf(wv.w) * sv.w;
            b2 += wv.x * vv.x + wv.y * vv.y + wv.z * vv.z + wv.w * vv.w;
        }
        As[tid] = a2;
        Bs[tid] = b2;
    }
    __syncthreads();

    if (!active) return;

    // --- pos gather (idx long since arrived) ---
    const float ax = pos[a * 3 + 0], ay = pos[a * 3 + 1], az = pos[a * 3 + 2];
    const float bx = pos[b * 3 + 0], by = pos[b * 3 + 1], bz = pos[b * 3 + 2];
    const float vx = ax - bx, vy = ay - by, vz = az - bz;
    const float d2 = vx * vx + vy * vy + vz * vz;
    const float d  = sqrtf(d2);
    const float un = d / (d + 1e-7f);      // ||unit||

    float acc[16];
    #pragma unroll
    for (int o = 0; o < 16; ++o) acc[o] = un * As[o];

    // edge-type block: feat in regs + uniform w_sca cols via s_load
    #pragma unroll
    for (int t = 0; t < E_FEAT; ++t) {
        #pragma unroll
        for (int o = 0; o < 16; ++o)
            acc[o] += f[t] * w_sca[o * W_SCA_COLS + DIM_HID + NUM_GAUSS + t];
    }

    // Gaussian smearing window: exp(-312.5*(d-0.04g)^2)
    {
        const float STEP = 10.0f / 250.0f;                       // 0.04
        const float INVS = 25.0f;
        const float C2   = -312.5f * 1.44269504088896340736f;    // coeff * log2(e)
        int glo = (int)ceilf((d - RAD) * INVS);
        int ghi = (int)floorf((d + RAD) * INVS);
        if (glo < 0) glo = 0;
        if (ghi > NUM_GAUSS - 1) ghi = NUM_GAUSS - 1;
        for (int g = glo; g <= ghi; ++g) {
            const float t = d - (float)g * STEP;
            const float w = exp2f(C2 * t * t);
            const float4* row = (const float4*)&wg[g * GP];
            const float4 w0 = row[0], w1 = row[1], w2 = row[2], w3 = row[3];
            acc[0]  += w * w0.x; acc[1]  += w * w0.y; acc[2]  += w * w0.z; acc[3]  += w * w0.w;
            acc[4]  += w * w1.x; acc[5]  += w * w1.y; acc[6]  += w * w1.z; acc[7]  += w * w1.w;
            acc[8]  += w * w2.x; acc[9]  += w * w2.y; acc[10] += w * w2.z; acc[11] += w * w2.w;
            acc[12] += w * w3.x; acc[13] += w * w3.y; acc[14] += w * w3.z; acc[15] += w * w3.w;
        }
    }

    // store out_sca now: retires store data early, overlaps with gate math
    float* o1 = out + (size_t)e * 16;
    #pragma unroll
    for (int o = 0; o < 16; o += 4)
        *(float4*)(o1 + o) = make_float4(acc[o], acc[o + 1], acc[o + 2], acc[o + 3]);

    // gates: w_gate/b_gate via uniform s_load; sigmoid via exp2 + fast rcp
    const float u2 = un * un;
    const float NL2E = -1.44269504088896340736f;
    float* o2 = out + (size_t)E * 16 + (size_t)e * 16;
    #pragma unroll
    for (int oq = 0; oq < 16; oq += 4) {
        float4 ov;
        float* po = (float*)&ov;
        #pragma unroll
        for (int oi = 0; oi < 4; ++oi) {
            const int o = oq + oi;
            float x = b_gate[o];
            #pragma unroll
            for (int p = 0; p < 16; ++p) x += acc[p] * w_gate[o * 16 + p];
            const float gate = __builtin_amdgcn_rcpf(1.0f + exp2f(NL2E * x));
            const float gv = gate * Bs[o];
            po[oi] = gv * gv * u2;
        }
        *(float4*)(o2 + oq) = ov;
    }
}

extern "C" void kernel_launch(void* const* d_in, const int* in_sizes, int n_in,
                              void* d_out, int out_size, void* d_ws, size_t ws_size,
                              hipStream_t stream) {
    const int*   idx    = (const int*)d_in[0];    // [2,E]
    const float* feat   = (const float*)d_in[1];  // [E,5]
    const float* pos    = (const float*)d_in[2];  // [N,3]
    const float* w_edge = (const float*)d_in[3];  // [64,1]
    const float* w_vec1 = (const float*)d_in[4];  // [64,64]
    const float* w_vec2 = (const float*)d_in[5];  // [16,64]
    const float* w_sca  = (const float*)d_in[6];  // [16,320]
    const float* w_gate = (const float*)d_in[7];  // [16,16]
    const float* b_gate = (const float*)d_in[8];  // [16]
    float* out = (float*)d_out;

    const int E = in_sizes[0] / 2;
    const int nblk = (E + 255) / 256;
    edge_kernel<<<nblk, 256, 0, stream>>>(idx, idx + E, feat, pos,
                                          w_edge, w_vec1, w_vec2,
                                          w_sca, w_gate, b_gate, out, E);
}